// Round 8
// baseline (335.378 us; speedup 1.0000x reference)
//
#include <hip/hip_runtime.h>
#include <hip/hip_fp16.h>

#define B_   8
#define CIN  256
#define T_   4096
#define TP   4097    // padded T (row 0 = zeros, row t+1 = x[t])
#define CO   256
#define O4   1024
#define KK   512
#define NN   32768   // B_*T_
#define NCH  128     // chunks along T
#define CL   32      // chunk length

// ws layout (float offsets)
#define OFF_XHI  0           // ushort [8][4097][256]
#define OFF_XLO  4195328
#define OFF_WHI  8390656     // ushort [1024][512]
#define OFF_WLO  8652800
#define OFF_F16  8914944     // ushort(f16) [8][4096][256]
#define OFF_IZ16 13109248
#define OFF_O16  17303552
#define OFF_A    21497856    // float [8][128][256]
#define OFF_B    21760000
#define OFF_C    22022144
// total 22,284,288 floats = 89.1 MB

typedef __attribute__((ext_vector_type(8))) short short8;
typedef __attribute__((ext_vector_type(4))) float floatx4;

__device__ __forceinline__ float fsig(float x)  { return 1.0f / (1.0f + __expf(-x)); }
__device__ __forceinline__ float ftanh(float x) { return 2.0f / (1.0f + __expf(-2.0f * x)) - 1.0f; }

__device__ __forceinline__ unsigned short bf16_rne(float v) {
    unsigned u = __float_as_uint(v);
    unsigned r = (u + 0x7fffu + ((u >> 16) & 1u)) >> 16;
    return (unsigned short)r;
}
__device__ __forceinline__ void split_bf16(float v, unsigned short& hi, unsigned short& lo) {
    hi = bf16_rne(v);
    float hf = __uint_as_float(((unsigned)hi) << 16);
    lo = bf16_rne(v - hf);
}

// async 16B/lane global->LDS DMA; lds base must be wave-uniform (dest = base + lane*16)
__device__ __forceinline__ void glds16(const unsigned short* g, unsigned short* l) {
    __builtin_amdgcn_global_load_lds(
        (const __attribute__((address_space(1))) unsigned*)g,
        (__attribute__((address_space(3))) unsigned*)l, 16, 0, 0);
}

// merged converts: bid<2048 -> W repack/split; bid>=2048 -> X transpose/split.
// W[o=g*256+c][i][j] -> Wa[r=c*4+g][k=j*256+i].  x[b][c][t] -> Xpad[b][t+1][c].
__global__ void convert_kernel(const float* __restrict__ W,
                               const float* __restrict__ x,
                               unsigned short* __restrict__ Whi,
                               unsigned short* __restrict__ Wlo,
                               unsigned short* __restrict__ Xhi,
                               unsigned short* __restrict__ Xlo) {
    __shared__ float tile[64][69];      // 69 mod 32 = 5 -> conflict-free both phases
    const int bid = blockIdx.x;
    const int tid = threadIdx.x;
    if (bid < 2048) {
        int e = bid * 256 + tid;        // 1024*512 elements
        int r = e >> 9, k = e & 511;
        int g = r & 3, c = r >> 2;
        int j = k >> 8, i = k & 255;
        float v = W[((size_t)((g << 8) + c)) * 512 + i * 2 + j];
        unsigned short hi, lo;
        split_bf16(v, hi, lo);
        Whi[e] = hi;
        Wlo[e] = lo;
        return;
    }
    const int b2 = bid - 2048;
    const int t0 = (b2 & 63) * 64;
    const int c0 = ((b2 >> 6) & 3) * 64;
    const int b  = b2 >> 8;

    {   // read: float4 along t, 16 rows per pass
        int j4 = (tid & 15) * 4, r16 = tid >> 4;
#pragma unroll
        for (int p = 0; p < 4; p++) {
            int i = p * 16 + r16;
            float4 v = *(const float4*)&x[((size_t)(b * 256 + c0 + i)) * T_ + t0 + j4];
            tile[i][j4] = v.x; tile[i][j4 + 1] = v.y;
            tile[i][j4 + 2] = v.z; tile[i][j4 + 3] = v.w;
        }
    }
    if (t0 == 0 && tid < 64) {   // zero pad row (x[-1] = 0)
        size_t z = (size_t)b * TP * 256 + c0 + tid;
        Xhi[z] = 0; Xlo[z] = 0;
    }
    __syncthreads();
    {   // write coalesced along c
        int i = tid & 63, jj = tid >> 6;
#pragma unroll
        for (int p = 0; p < 16; p++) {
            int t = jj * 16 + p;
            float v = tile[i][t];
            unsigned short hi, lo;
            split_bf16(v, hi, lo);
            size_t idx = ((size_t)b * TP + t0 + t + 1) * 256 + c0 + i;
            Xhi[idx] = hi;
            Xlo[idx] = lo;
        }
    }
}

// C[r=1024][n=32768] = Wa · Xb^T, split-bf16 MFMA (3 products), 128x128 tile, BK=32,
// single-buffered LDS (32 KB total) -> 5 blocks/CU; barrier-phase stalls of one
// block hidden by the other four. Epilogue: f16 gates in LDS -> uint4 stores
// + fused per-chunk scan summaries.
__launch_bounds__(256, 5)
__global__ void gemm_mfma_kernel(const unsigned short* __restrict__ Xhi,
                                 const unsigned short* __restrict__ Xlo,
                                 const unsigned short* __restrict__ Whi,
                                 const unsigned short* __restrict__ Wlo,
                                 const float* __restrict__ bias,
                                 __half* __restrict__ fw,
                                 __half* __restrict__ izw,
                                 __half* __restrict__ ow,
                                 float* __restrict__ Aw,
                                 float* __restrict__ Bw)
{
    __shared__ __align__(16) unsigned short smem_us[16384];   // 32 KB
    unsigned short* pA_hi = smem_us;                          // [128][32] each
    unsigned short* pA_lo = smem_us + 4096;
    unsigned short* pB_hi = smem_us + 8192;
    unsigned short* pB_lo = smem_us + 12288;
    // epilogue aliases (after K-loop): __half [128][40] x3 = 30,720 B
    __half* epf = (__half*)smem_us;
    __half* epz = (__half*)(smem_us + 5120);
    __half* epo = (__half*)(smem_us + 10240);

    const int tid  = threadIdx.x;
    const int wave = tid >> 6, lane = tid & 63;
    const int q = lane >> 4, mr = lane & 15;

    // grid map: XCD(=bid%8) keeps one X-tile for all 8 r-blocks; W L2-resident
    const int bid    = blockIdx.x;
    const int n_sub  = bid & 7;
    const int r_blk  = (bid >> 3) & 7;
    const int n_blk  = (bid >> 6) * 8 + n_sub;
    const int r0 = r_blk * 128;
    const int n0 = n_blk * 128;
    const int bb = n0 >> 12;
    const int t0 = n0 & (T_ - 1);
    const int m_base = (wave & 1) * 64;
    const int n_base = (wave >> 1) * 64;

    // staging: wave w stages rows 32w..32w+31 of each array; 2 DMA instrs/array
    const int lrow = lane >> 2;            // 0..15
    const int lg   = (lane & 3) * 8;       // ushort offset in row
    const size_t wA0 = (size_t)(r0 + wave * 32 + lrow) * 512 + lg;
    const size_t wA1 = wA0 + 16 * 512;
    const size_t xB0 = ((size_t)bb * TP + t0 + wave * 32 + lrow) * 256 + lg;
    const size_t xB1 = xB0 + 16 * 256;
    unsigned short* sAh = pA_hi + wave * 1024;   // wave-uniform LDS bases
    unsigned short* sAl = pA_lo + wave * 1024;
    unsigned short* sBh = pB_hi + wave * 1024;
    unsigned short* sBl = pB_lo + wave * 1024;

    floatx4 acc[4][4];
#pragma unroll
    for (int v = 0; v < 4; v++)
#pragma unroll
        for (int u = 0; u < 4; u++) acc[v][u] = (floatx4){0.f, 0.f, 0.f, 0.f};

    for (int i = 0; i < 16; i++) {
        const int kk = i * 32;
        __syncthreads();   // prior iter's frag reads done -> safe to overwrite
        glds16(Whi + wA0 + kk, sAh);
        glds16(Whi + wA1 + kk, sAh + 512);
        glds16(Wlo + wA0 + kk, sAl);
        glds16(Wlo + wA1 + kk, sAl + 512);
        glds16(Xhi + xB0 + kk, sBh);
        glds16(Xhi + xB1 + kk, sBh + 512);
        glds16(Xlo + xB0 + kk, sBl);
        glds16(Xlo + xB1 + kk, sBl + 512);
        __syncthreads();   // DMA visible (drain hidden by other 4 blocks/CU)

        short8 ah[4], al[4], bh[4], bl[4];
#pragma unroll
        for (int v = 0; v < 4; v++) {
            int m = m_base + v * 16 + mr;
            ah[v] = *(const short8*)(pA_hi + m * 32 + q * 8);
            al[v] = *(const short8*)(pA_lo + m * 32 + q * 8);
        }
#pragma unroll
        for (int u = 0; u < 4; u++) {
            int n = n_base + u * 16 + mr;
            bh[u] = *(const short8*)(pB_hi + n * 32 + q * 8);
            bl[u] = *(const short8*)(pB_lo + n * 32 + q * 8);
        }

#pragma unroll
        for (int v = 0; v < 4; v++)
#pragma unroll
            for (int u = 0; u < 4; u++)
                acc[v][u] = __builtin_amdgcn_mfma_f32_16x16x32_bf16(ah[v], bh[u], acc[v][u], 0, 0, 0);
#pragma unroll
        for (int v = 0; v < 4; v++)
#pragma unroll
            for (int u = 0; u < 4; u++)
                acc[v][u] = __builtin_amdgcn_mfma_f32_16x16x32_bf16(ah[v], bl[u], acc[v][u], 0, 0, 0);
#pragma unroll
        for (int v = 0; v < 4; v++)
#pragma unroll
            for (int u = 0; u < 4; u++)
                acc[v][u] = __builtin_amdgcn_mfma_f32_16x16x32_bf16(al[v], bh[u], acc[v][u], 0, 0, 0);
    }

    // ---------- epilogue ----------
    __syncthreads();                     // all fragment reads done; LDS repurposed
#pragma unroll
    for (int v = 0; v < 4; v++) {
        int cl = (m_base >> 2) + v * 4 + q;          // local channel 0..31
        int c  = (r0 >> 2) + cl;
        float bz = bias[c], bf_ = bias[256 + c], bo = bias[512 + c], bi = bias[768 + c];
#pragma unroll
        for (int u = 0; u < 4; u++) {
            int t_l = n_base + u * 16 + mr;
            float zv = ftanh(acc[v][u][0] + bz);
            float iv = fsig(acc[v][u][3] + bi);
            int off = t_l * 40 + cl;
            epf[off] = __float2half(fsig(acc[v][u][1] + bf_));
            epz[off] = __float2half(iv * zv);
            epo[off] = __float2half(fsig(acc[v][u][2] + bo));
        }
    }
    __syncthreads();

    // coalesced f16 stores: thread -> t_r = tid>>1, 16 consecutive c (32 B = 2x uint4)
    {
        const int t_r = tid >> 1;
        const int cb = (tid & 1) << 4;
        const size_t gbase = ((size_t)bb * T_ + t0 + t_r) * 256 + (r0 >> 2) + cb;
        const int lbase = t_r * 40 + cb;      // __half index; byte offset 16B-aligned
        uint4 v0, v1;
        v0 = *(const uint4*)&epf[lbase];  v1 = *(const uint4*)&epf[lbase + 8];
        *(uint4*)&fw[gbase] = v0;  *(uint4*)&fw[gbase + 8] = v1;
        v0 = *(const uint4*)&epz[lbase];  v1 = *(const uint4*)&epz[lbase + 8];
        *(uint4*)&izw[gbase] = v0; *(uint4*)&izw[gbase + 8] = v1;
        v0 = *(const uint4*)&epo[lbase];  v1 = *(const uint4*)&epo[lbase + 8];
        *(uint4*)&ow[gbase] = v0;  *(uint4*)&ow[gbase + 8] = v1;
    }

    // fused scan phase 1: per-chunk (A = prod f, B = affine end) from LDS
    if (tid < 128) {
        const int chunk = tid >> 5, cc = tid & 31;
        float A = 1.0f, Bv = 0.0f;
        int base = (chunk * 32) * 40 + cc;
#pragma unroll 4
        for (int j = 0; j < 32; j++) {
            float f  = __half2float(epf[base + j * 40]);
            float iz = __half2float(epz[base + j * 40]);
            Bv = fmaf(f, Bv, iz);
            A *= f;
        }
        const int chunk_abs = (t0 >> 5) + chunk;
        const size_t aidx = ((size_t)bb * NCH + chunk_abs) * 256 + (r0 >> 2) + cc;
        Aw[aidx] = A;
        Bw[aidx] = Bv;
    }
}

// Phase 2: exclusive scan over chunk summaries; loads batched 16-wide to pipeline
__global__ void scan_phase2(const float* __restrict__ Aw, const float* __restrict__ Bw,
                            float* __restrict__ cw)
{
    int b = blockIdx.x, c = threadIdx.x;
    float carry = 0.0f;
    for (int ch0 = 0; ch0 < NCH; ch0 += 16) {
        float Ar[16], Br[16], cv[16];
#pragma unroll
        for (int j = 0; j < 16; j++) {
            size_t idx = ((size_t)(b * NCH + ch0 + j)) * CO + c;
            Ar[j] = Aw[idx];
            Br[j] = Bw[idx];
        }
#pragma unroll
        for (int j = 0; j < 16; j++) {
            cv[j] = carry;
            carry = fmaf(Ar[j], carry, Br[j]);
        }
#pragma unroll
        for (int j = 0; j < 16; j++)
            cw[((size_t)(b * NCH + ch0 + j)) * CO + c] = cv[j];
    }
}

// Phase 3: replay recurrence with carry, h = o*c, transpose [t][c] -> out[b][c][t]
// writes as float4 along t (1 KB per wave-instr)
__global__ void scan_phase3(const __half* __restrict__ fw, const __half* __restrict__ izw,
                            const __half* __restrict__ ow, const float* __restrict__ cw,
                            float* __restrict__ out)
{
    __shared__ float hbuf[CL][257];
    int b = blockIdx.y, ch = blockIdx.x, c = threadIdx.x;
    float cs = cw[((size_t)(b * NCH + ch)) * CO + c];
    size_t base = ((size_t)(b * T_ + ch * CL)) * CO + c;
#pragma unroll 4
    for (int tt = 0; tt < CL; tt++) {
        float f  = __half2float(fw[base + (size_t)tt * CO]);
        float iz = __half2float(izw[base + (size_t)tt * CO]);
        float o  = __half2float(ow[base + (size_t)tt * CO]);
        cs = fmaf(f, cs, iz);
        hbuf[tt][c] = o * cs;
    }
    __syncthreads();
    const int j4 = (threadIdx.x & 7) * 4;
    const int cc0 = threadIdx.x >> 3;     // 0..31
#pragma unroll
    for (int w = 0; w < 8; w++) {
        int cc = cc0 + w * 32;
        float4 hv = { hbuf[j4][cc], hbuf[j4 + 1][cc], hbuf[j4 + 2][cc], hbuf[j4 + 3][cc] };
        *(float4*)&out[((size_t)(b * CO + cc)) * T_ + ch * CL + j4] = hv;
    }
}

extern "C" void kernel_launch(void* const* d_in, const int* in_sizes, int n_in,
                              void* d_out, int out_size, void* d_ws, size_t ws_size,
                              hipStream_t stream) {
    const float* x    = (const float*)d_in[0];
    const float* W    = (const float*)d_in[1];
    const float* bias = (const float*)d_in[2];
    float* out = (float*)d_out;
    float* ws  = (float*)d_ws;

    unsigned short* Xhi = (unsigned short*)(ws + OFF_XHI);
    unsigned short* Xlo = (unsigned short*)(ws + OFF_XLO);
    unsigned short* Whi = (unsigned short*)(ws + OFF_WHI);
    unsigned short* Wlo = (unsigned short*)(ws + OFF_WLO);
    __half* fw  = (__half*)(ws + OFF_F16);
    __half* izw = (__half*)(ws + OFF_IZ16);
    __half* ow  = (__half*)(ws + OFF_O16);
    float* Aw  = ws + OFF_A;
    float* Bw  = ws + OFF_B;
    float* cw  = ws + OFF_C;

    convert_kernel<<<4096, 256, 0, stream>>>(W, x, Whi, Wlo, Xhi, Xlo);
    gemm_mfma_kernel<<<(NN / 128) * (O4 / 128), 256, 0, stream>>>(
        Xhi, Xlo, Whi, Wlo, bias, fw, izw, ow, Aw, Bw);
    scan_phase2<<<B_, CO, 0, stream>>>(Aw, Bw, cw);
    scan_phase3<<<dim3(NCH, B_), CO, 0, stream>>>(fw, izw, ow, cw, out);
}